// Round 15
// baseline (1913.893 us; speedup 1.0000x reference)
//
#include <hip/hip_runtime.h>
#include <cstdint>
#include <cstddef>

#define T_DIM 128
#define B_DIM 256
#define F_DIM 512
#define H_DIM 1024
#define G_DIM 4096   // 4*H
#define NT    16     // fused-pipeline chunk size

typedef unsigned short u16;
typedef unsigned short u16x8 __attribute__((ext_vector_type(8)));
typedef unsigned short u16x4 __attribute__((ext_vector_type(4)));
typedef __bf16 bf16x8 __attribute__((ext_vector_type(8)));
typedef float f32x4 __attribute__((ext_vector_type(4)));
typedef unsigned long long u64;

__device__ __forceinline__ float bf2f(u16 u) {
    union { unsigned v; float f; } x; x.v = ((unsigned)u) << 16; return x.f;
}
__device__ __forceinline__ u16 f2bf(float f) {
    union { float f; unsigned v; } x; x.f = f;
    return (u16)((x.v + 0x7fffu + ((x.v >> 16) & 1u)) >> 16);
}

__device__ __forceinline__ f32x4 mfma16(u16x8 a, u16x8 b, f32x4 c) {
    return __builtin_amdgcn_mfma_f32_16x16x32_bf16(
        __builtin_bit_cast(bf16x8, a), __builtin_bit_cast(bf16x8, b), c, 0, 0, 0);
}

// AUX = cache-policy (LLVM CPol): SC0=1, SC1=16. 17 = coherent (L3) read.
template <int AUX>
__device__ __forceinline__ void gl_lds16(const void* g, void* s) {
    __builtin_amdgcn_global_load_lds(
        (const __attribute__((address_space(1))) void*)g,
        (__attribute__((address_space(3))) void*)s, 16, 0, AUX);
}

__device__ __forceinline__ float sigm(float x) { return 1.0f / (1.0f + __expf(-x)); }
__device__ __forceinline__ float tanh_fast(float x) {
    float e = __expf(2.0f * x);
    return 1.0f - 2.0f / (e + 1.0f);
}

// ---------------------------------------------------------------------------
// GEMM tile as a device function (blockDim 256, 4 waves 2x2).
// WT=1: write-through C stores for same-launch consumers. AUXA=17: coherent
// A staging (A written same-launch, write-through).
// ---------------------------------------------------------------------------
template <int EPI, int WT, int AUXA>
__device__ void gemm_tile(char* smraw, const u16* __restrict__ A,
                          const u16* __restrict__ B, const float* __restrict__ bias,
                          u16* __restrict__ C, int K, int N, int bm, int bn) {
    u16* smem = (u16*)smraw;
    u16* lA = smem;
    u16* lB = smem + 8192;
    const int lane = threadIdx.x & 63;
    const int wave = threadIdx.x >> 6;
    const int wr = wave >> 1, wc = wave & 1;
    f32x4 acc[4][4] = {};
    const int srow = lane >> 3;
    const int scol = (lane & 7) * 8;
    const u16* Abase = A + (size_t)(bm * 128 + srow) * K + scol;
    const u16* Bbase = B + (size_t)(bn * 128 + srow) * K + scol;

    for (int k0 = 0; k0 < K; k0 += 64) {
#pragma unroll
        for (int j = 0; j < 4; ++j) {
            int chunk = wave * 4 + j;
            gl_lds16<AUXA>(Abase + (size_t)(chunk * 8) * K + k0, lA + chunk * 512);
            gl_lds16<0>(Bbase + (size_t)(chunk * 8) * K + k0, lB + chunk * 512);
        }
        __syncthreads();
        const u16* pA = lA + (wr * 64 + (lane & 15)) * 64 + (lane >> 4) * 8;
        const u16* pB = lB + (wc * 64 + (lane & 15)) * 64 + (lane >> 4) * 8;
#pragma unroll
        for (int kk = 0; kk < 2; ++kk) {
            u16x8 a[4], b[4];
#pragma unroll
            for (int m = 0; m < 4; ++m) a[m] = *(const u16x8*)(pA + m * 1024 + kk * 32);
#pragma unroll
            for (int n = 0; n < 4; ++n) b[n] = *(const u16x8*)(pB + n * 1024 + kk * 32);
#pragma unroll
            for (int m = 0; m < 4; ++m)
#pragma unroll
                for (int n = 0; n < 4; ++n)
                    acc[m][n] = mfma16(a[m], b[n], acc[m][n]);
        }
        __syncthreads();
    }
#pragma unroll
    for (int n = 0; n < 4; ++n) {
        int cc = wc * 64 + n * 16 + (lane & 15);
        float bv = bias[bn * 128 + cc];
#pragma unroll
        for (int m = 0; m < 4; ++m) {
            int rr = wr * 64 + m * 16 + ((lane >> 4) * 4);
#pragma unroll
            for (int i = 0; i < 4; ++i) {
                float v = acc[m][n][i] + bv;
                if (EPI == 1) v = (v >= 0.0f) ? v : 0.01f * v;
                smem[(rr + i) * 136 + cc] = f2bf(v);
            }
        }
    }
    __syncthreads();
#pragma unroll
    for (int p = 0; p < 8; ++p) {
        int rr = p * 16 + wave * 4 + (lane >> 4);
        int cc = (lane & 15) * 8;
        u16x8 v = *(const u16x8*)(smem + rr * 136 + cc);
        u16* dst = C + (size_t)(bm * 128 + rr) * N + bn * 128 + cc;
        if (WT) {
            union { u16x8 h; u64 q[2]; } u; u.h = v;
            __hip_atomic_store((u64*)dst, u.q[0], __ATOMIC_RELAXED, __HIP_MEMORY_SCOPE_AGENT);
            __hip_atomic_store((u64*)dst + 1, u.q[1], __ATOMIC_RELAXED, __HIP_MEMORY_SCOPE_AGENT);
        } else {
            *(u16x8*)dst = v;
        }
    }
    __syncthreads();   // smem reusable by the next tile
}

// standalone wrapper (prologue)
template <int EPI>
__global__ __launch_bounds__(256) void gemm_bt128(
    const u16* __restrict__ A, const u16* __restrict__ B,
    const float* __restrict__ bias, u16* __restrict__ C, int K, int N) {
    __shared__ __align__(16) char smem[128 * 136 * 2];
    gemm_tile<EPI, 0, 0>(smem, A, B, bias, C, K, N, blockIdx.x, blockIdx.y);
}

// ---------------------------------------------------------------------------
// FUSED kernel, grid 512 x 256:
//   blocks 0..255  : persistent LSTM recurrence (R13 structure), waves at
//                    PRIORITY 3 — the latency chain must win CU issue slots.
//   blocks 256..511: GEMM1+GEMM2 producing xg for chunk k+1, waves at
//                    PRIORITY 0 — soak idle cycles only (T5 mechanism).
// R14 (no prio) doubled the lstm step latency via same-CU issue arbitration.
// ---------------------------------------------------------------------------
__global__ __launch_bounds__(256, 1) void fused_step(
    const u16* __restrict__ xg, const u16* __restrict__ Whh,
    const int* __restrict__ dones, const float* __restrict__ Wv,
    u16* __restrict__ h0, u16* __restrict__ h1,
    float* __restrict__ cbuf, float* __restrict__ hbuf,
    float* __restrict__ value, int* __restrict__ flags,
    float* __restrict__ vpartial, int t0, int nt, int first,
    int MT, int kidx, const u16* __restrict__ x_bf, const u16* __restrict__ W1b,
    const float* __restrict__ b1, u16* __restrict__ shr,
    const u16* __restrict__ Wih, const float* __restrict__ bcomb,
    u16* __restrict__ xg_next, int* __restrict__ g1cnt) {
    __shared__ __align__(16) char sm[65536];
    const int bid = blockIdx.x;
    const int tid = threadIdx.x;

    if (bid >= 256) {
        __builtin_amdgcn_s_setprio(0);   // background: never out-arbitrate lstm
        if (MT == 0) return;
        const int g = bid - 256;
        // ---- GEMM1: shr = leaky(x_bf @ W1^T + b1), MT*8 tiles ----
        for (int id = g; id < MT * 8; id += 256) {
            gemm_tile<1, 1, 0>(sm, x_bf, W1b, b1, shr, F_DIM, H_DIM, id >> 3, id & 7);
            if (tid == 0)
                __hip_atomic_fetch_add(&g1cnt[id >> 3], 1, __ATOMIC_RELAXED,
                                       __HIP_MEMORY_SCOPE_AGENT);
        }
        // ---- GEMM2: xg_next = shr @ Wih_p^T + bcomb, MT*32 tiles ----
        const int target = 8 * (kidx + 1);
        for (int id = g; id < MT * 32; id += 256) {
            int bmp = id >> 5, bnp = id & 31;
            while (__hip_atomic_load(&g1cnt[bmp], __ATOMIC_RELAXED,
                                     __HIP_MEMORY_SCOPE_AGENT) < target)
                __builtin_amdgcn_s_sleep(2);
            gemm_tile<0, 0, 17>(sm, shr, Wih, bcomb, xg_next, H_DIM, G_DIM, bmp, bnp);
        }
        return;
    }

    // ======================= LSTM half (R13, prio 3) =======================
    __builtin_amdgcn_s_setprio(3);       // latency-critical: always win issue
    float* lepi = (float*)sm;
    char* hbB = sm + 17408;
    float* vpB = (float*)(sm + 19456);
    const int lane = tid & 63, wave = tid >> 6;
    const int bm = bid & 3, bn = bid >> 2;
    const int sw = (lane & 7) << 4;

    u16x8 breg[32];
    {
        const u16* wrow = Whh + (size_t)(bn * 64 + wave * 16 + (lane & 15)) * H_DIM +
                          (lane >> 4) * 8;
#pragma unroll
        for (int s = 0; s < 32; ++s) breg[s] = *(const u16x8*)(wrow + s * 32);
    }

    const int r = tid & 63;
    const int ublk = tid >> 6;
    const int bg = bm * 64 + r;
    const int ucol = bn * 16 + ublk * 4;
    float wv[4], c[4];
#pragma unroll
    for (int uu = 0; uu < 4; ++uu) wv[uu] = Wv[ucol + uu];
    if (first) {
        c[0] = c[1] = c[2] = c[3] = 0.0f;
    } else {
        float4 cv = *(const float4*)(cbuf + (size_t)bg * H_DIM + ucol);
        c[0] = cv.x; c[1] = cv.y; c[2] = cv.z; c[3] = cv.w;
    }

    const int rl = lane & 15;
    const int ko = (lane >> 4) * 16;

    for (int tt = 0; tt < nt; ++tt) {
        const int t = t0 + tt;
        const char* hinB = (const char*)((t & 1) ? h1 : h0);
        u16* houtB = (t & 1) ? h0 : h1;

        auto poll16 = [&](int kc) {
            if (t > 0) {
                const int fi = bm * 64 + kc * 16 + (lane & 15);
                while (__hip_atomic_load(&flags[fi], __ATOMIC_RELAXED,
                                         __HIP_MEMORY_SCOPE_AGENT) < t)
                    __builtin_amdgcn_s_sleep(1);
            }
        };
        auto stage_chunk_blk = [&](char* buf, int kc) {
#pragma unroll
            for (int j = 0; j < 8; ++j) {
                int hr = wave * 8 + j;
                int rr = hr * 2 + (lane >> 5);
                int sc = ((lane & 31) * 16) ^ ((rr & 7) << 4);
                int cbg = kc * 512 + sc;
                gl_lds16<17>(hinB + (size_t)(cbg >> 5) * 8192 + bm * 2048 + rr * 32 +
                             (cbg & 31), buf + (size_t)hr * 1024);
            }
        };

        const int done = dones[t * B_DIM + bg];
        u16x4 xv[4];
#pragma unroll
        for (int uu = 0; uu < 4; ++uu)
            xv[uu] = *(const u16x4*)(xg + (size_t)tt * B_DIM * G_DIM +
                                     (size_t)bg * G_DIM + bn * 64 + (ublk * 4 + uu) * 4);

        poll16(0);
        stage_chunk_blk(sm, 0);
        poll16(1);
        __syncthreads();   // B1

        f32x4 acc[4] = {};
#pragma unroll
        for (int kc = 0; kc < 4; ++kc) {
            char* buf = sm + (kc & 1) * 32768;
            if (kc < 3) stage_chunk_blk(sm + ((kc + 1) & 1) * 32768, kc + 1);
#pragma unroll
            for (int s2 = 0; s2 < 8; ++s2) {
                int kb2 = s2 * 64 + ko;
#pragma unroll
                for (int m = 0; m < 4; ++m) {
                    u16x8 a = *(const u16x8*)(buf + (m * 16 + rl) * 512 + (kb2 ^ sw));
                    acc[m] = mfma16(a, breg[kc * 8 + s2], acc[m]);
                }
            }
            if (kc < 2) poll16(kc + 2);
            if (kc < 3) __syncthreads();   // B2..B4
        }

        if (t > 0 && tid < 64) {
            const float* vp = vpartial + (size_t)((t - 1) & 1) * 65536 +
                              (size_t)lane * 1024 + (size_t)(bm * 64 + bn) * 4;
            union { u64 u; float f[2]; } ua, ub;
            ua.u = __hip_atomic_load((const u64*)vp, __ATOMIC_RELAXED,
                                     __HIP_MEMORY_SCOPE_AGENT);
            ub.u = __hip_atomic_load((const u64*)(vp + 2), __ATOMIC_RELAXED,
                                     __HIP_MEMORY_SCOPE_AGENT);
            float s = ua.f[0] + ua.f[1] + ub.f[0] + ub.f[1];
#pragma unroll
            for (int m2 = 32; m2 >= 1; m2 >>= 1) s += __shfl_xor(s, m2);
            if (tid == 0) value[(t - 1) * B_DIM + bm * 64 + bn] += s;
        }

#pragma unroll
        for (int m = 0; m < 4; ++m)
#pragma unroll
            for (int i = 0; i < 4; ++i)
                lepi[(m * 16 + (lane >> 4) * 4 + i) * 65 + wave * 16 + rl] = acc[m][i];
        // no barrier: wave-local columns

        const float mb = (done == 0) ? 1.0f : 0.0f;
        float vpart = 0.0f;
        u16x4 hb;
        float hf[4];
#pragma unroll
        for (int uu = 0; uu < 4; ++uu) {
            const float* gp = &lepi[r * 65 + (ublk * 4 + uu) * 4];
            float gi = bf2f(xv[uu][0]) + mb * gp[0];
            float gf = bf2f(xv[uu][1]) + mb * gp[1];
            float gg = bf2f(xv[uu][2]) + mb * gp[2];
            float go = bf2f(xv[uu][3]) + mb * gp[3];
            float i_ = sigm(gi), f_ = sigm(gf), g_ = tanh_fast(gg), o_ = sigm(go);
            float cn = f_ * (mb * c[uu]) + i_ * g_;
            float hn = o_ * tanh_fast(cn);
            c[uu] = cn; hf[uu] = hn;
            hb[uu] = f2bf(hn);
            float lr = (hn >= 0.0f) ? hn : 0.01f * hn;
            vpart += lr * wv[uu];
        }
        *(u16x4*)(hbB + r * 32 + ublk * 8) = hb;
        vpB[r * 4 + ublk] = vpart;
        if (t == T_DIM - 1)
            *(float4*)(hbuf + (size_t)bg * H_DIM + ucol) = make_float4(hf[0], hf[1], hf[2], hf[3]);
        __syncthreads();   // B5

        {
            u64 hv = *(const u64*)(hbB + tid * 8);
            __hip_atomic_store((u64*)((char*)houtB + (size_t)bn * 8192 + bm * 2048 + tid * 8),
                               hv, __ATOMIC_RELAXED, __HIP_MEMORY_SCOPE_AGENT);
            if (tid < 64) {
                const u64* pv = (const u64*)vpB + tid * 2;
                u64 v0 = pv[0], v1 = pv[1];
                float* dv = vpartial + (size_t)(t & 1) * 65536 + (size_t)bn * 1024 +
                            bm * 256 + tid * 4;
                __hip_atomic_store((u64*)dv, v0, __ATOMIC_RELAXED, __HIP_MEMORY_SCOPE_AGENT);
                __hip_atomic_store((u64*)dv + 1, v1, __ATOMIC_RELAXED, __HIP_MEMORY_SCOPE_AGENT);
            }
        }
        __syncthreads();   // B6: all waves' stores drained
        if (tid == 0)
            __hip_atomic_store(&flags[bm * 64 + bn], t + 1, __ATOMIC_RELAXED,
                               __HIP_MEMORY_SCOPE_AGENT);
    }
    *(float4*)(cbuf + (size_t)bg * H_DIM + ucol) = make_float4(c[0], c[1], c[2], c[3]);

    if (t0 + nt == T_DIM && tid < 64) {
        while (__hip_atomic_load(&flags[bm * 64 + lane], __ATOMIC_RELAXED,
                                 __HIP_MEMORY_SCOPE_AGENT) < T_DIM)
            __builtin_amdgcn_s_sleep(1);
        const float* vp = vpartial + (size_t)((T_DIM - 1) & 1) * 65536 +
                          (size_t)lane * 1024 + (size_t)(bm * 64 + bn) * 4;
        union { u64 u; float f[2]; } ua, ub;
        ua.u = __hip_atomic_load((const u64*)vp, __ATOMIC_RELAXED, __HIP_MEMORY_SCOPE_AGENT);
        ub.u = __hip_atomic_load((const u64*)(vp + 2), __ATOMIC_RELAXED,
                                 __HIP_MEMORY_SCOPE_AGENT);
        float s = ua.f[0] + ua.f[1] + ub.f[0] + ub.f[1];
#pragma unroll
        for (int m2 = 32; m2 >= 1; m2 >>= 1) s += __shfl_xor(s, m2);
        if (tid == 0) value[(T_DIM - 1) * B_DIM + bm * 64 + bn] += s;
    }
}

// ---------------------------------------------------------------------------
__global__ void k_cast_bf16(const float* __restrict__ in, u16* __restrict__ out, int n4) {
    int i = blockIdx.x * 256 + threadIdx.x;
    if (i < n4) {
        float4 v = *(const float4*)(in + (size_t)i * 4);
        u16x4 o;
        o[0] = f2bf(v.x); o[1] = f2bf(v.y); o[2] = f2bf(v.z); o[3] = f2bf(v.w);
        *(u16x4*)(out + (size_t)i * 4) = o;
    }
}

__global__ void k_permute_w(const float* __restrict__ W, u16* __restrict__ Wp) {
    int row = blockIdx.x;
    int rin = (row & 3) * H_DIM + (row >> 2);
    int c = threadIdx.x * 4;
    float4 v = *(const float4*)(W + (size_t)rin * H_DIM + c);
    u16x4 o;
    o[0] = f2bf(v.x); o[1] = f2bf(v.y); o[2] = f2bf(v.z); o[3] = f2bf(v.w);
    *(u16x4*)(Wp + (size_t)row * H_DIM + c) = o;
}

__global__ void k_prep_bias(const float* __restrict__ b_ih, const float* __restrict__ b_hh,
                            float* __restrict__ bc) {
    int i = blockIdx.x * 256 + threadIdx.x;
    int n = i >> 2, q = i & 3;
    bc[i] = b_ih[q * H_DIM + n] + b_hh[q * H_DIM + n];
}

__global__ void k_init(float* __restrict__ value, const float* __restrict__ bv,
                       u16* __restrict__ h0, int* __restrict__ flags,
                       int* __restrict__ g1cnt) {
    int i = blockIdx.x * 256 + threadIdx.x;
    if (i < B_DIM * H_DIM) h0[i] = 0;
    if (i < T_DIM * B_DIM) value[i] = *bv;
    if (i < 256) flags[i] = 0;
    if (i < 128) g1cnt[i] = 0;
}

extern "C" void kernel_launch(void* const* d_in, const int* in_sizes, int n_in,
                              void* d_out, int out_size, void* d_ws, size_t ws_size,
                              hipStream_t stream) {
    const float* x     = (const float*)d_in[0];
    const int*   dones = (const int*)d_in[1];
    const float* W1    = (const float*)d_in[2];
    const float* b1    = (const float*)d_in[3];
    const float* W_ih  = (const float*)d_in[4];
    const float* W_hh  = (const float*)d_in[5];
    const float* b_ih  = (const float*)d_in[6];
    const float* b_hh  = (const float*)d_in[7];
    const float* Wv    = (const float*)d_in[8];
    const float* bv    = (const float*)d_in[9];

    float* out   = (float*)d_out;
    float* value = out;                          // [T*B]
    float* hbuf  = out + (size_t)T_DIM * B_DIM;  // h_T [B*H] f32
    float* cbuf  = hbuf + (size_t)B_DIM * H_DIM; // c_T [B*H] f32

    char* ws = (char*)d_ws;
    size_t off = 0;
    auto alloc = [&](size_t bytes) {
        void* p = ws + off;
        off = (off + bytes + 255) & ~(size_t)255;
        return p;
    };
    const int nt = NT;                    // 16
    const int chunks = T_DIM / nt;        // 8
    const int MT = 2 * nt;                // 32 row-blocks of 128 per chunk

    u16*   x_bf   = (u16*)alloc((size_t)T_DIM * B_DIM * F_DIM * 2);
    u16*   shr    = (u16*)alloc((size_t)nt * B_DIM * H_DIM * 2);
    u16*   xgA    = (u16*)alloc((size_t)nt * B_DIM * G_DIM * 2);
    u16*   xgB    = (u16*)alloc((size_t)nt * B_DIM * G_DIM * 2);
    u16*   W1b    = (u16*)alloc((size_t)H_DIM * F_DIM * 2);
    u16*   Wihp   = (u16*)alloc((size_t)G_DIM * H_DIM * 2);
    u16*   Whhp   = (u16*)alloc((size_t)G_DIM * H_DIM * 2);
    float* bcomb  = (float*)alloc((size_t)G_DIM * 4);
    u16*   hping  = (u16*)alloc((size_t)B_DIM * H_DIM * 2);
    u16*   hpong  = (u16*)alloc((size_t)B_DIM * H_DIM * 2);
    int*   flags  = (int*)alloc(256 * 4);
    int*   g1cnt  = (int*)alloc(128 * 4);
    float* vpart  = (float*)alloc(2 * 65536 * 4);

    // ---- prologue: weight prep + cast ALL x + GEMMs for chunk 0 ----
    k_cast_bf16<<<(T_DIM * B_DIM * F_DIM / 4) / 256, 256, 0, stream>>>(
        x, x_bf, T_DIM * B_DIM * F_DIM / 4);
    k_cast_bf16<<<(H_DIM * F_DIM / 4) / 256, 256, 0, stream>>>(W1, W1b, H_DIM * F_DIM / 4);
    k_permute_w<<<G_DIM, 256, 0, stream>>>(W_ih, Wihp);
    k_permute_w<<<G_DIM, 256, 0, stream>>>(W_hh, Whhp);
    k_prep_bias<<<G_DIM / 256, 256, 0, stream>>>(b_ih, b_hh, bcomb);
    k_init<<<(B_DIM * H_DIM) / 256, 256, 0, stream>>>(value, bv, hping, flags, g1cnt);

    gemm_bt128<1><<<dim3(MT, H_DIM / 128), 256, 0, stream>>>(
        x_bf, W1b, b1, shr, F_DIM, H_DIM);
    gemm_bt128<0><<<dim3(MT, G_DIM / 128), 256, 0, stream>>>(
        shr, Wihp, bcomb, xgA, H_DIM, G_DIM);

    // ---- fused pipeline: lstm(chunk k, prio3) || gemms(chunk k+1, prio0) ----
    for (int k = 0; k < chunks; ++k) {
        const u16* xg_cur = (k & 1) ? xgB : xgA;
        u16* xg_nxt = (k & 1) ? xgA : xgB;
        int mt = (k + 1 < chunks) ? MT : 0;
        fused_step<<<512, 256, 0, stream>>>(
            xg_cur, Whhp, dones, Wv, hping, hpong, cbuf, hbuf, value, flags, vpart,
            k * nt, nt, (k == 0) ? 1 : 0,
            mt, k, x_bf + (size_t)(k + 1) * nt * B_DIM * F_DIM, W1b, b1, shr,
            Wihp, bcomb, xg_nxt, g1cnt);
    }
}

// Round 16
// 1511.147 us; speedup vs baseline: 1.2665x; 1.2665x over previous
//
#include <hip/hip_runtime.h>
#include <cstdint>
#include <cstddef>

#define T_DIM 128
#define B_DIM 256
#define F_DIM 512
#define H_DIM 1024
#define G_DIM 4096   // 4*H

typedef unsigned short u16;
typedef unsigned short u16x8 __attribute__((ext_vector_type(8)));
typedef unsigned short u16x4 __attribute__((ext_vector_type(4)));
typedef __bf16 bf16x8 __attribute__((ext_vector_type(8)));
typedef float f32x4 __attribute__((ext_vector_type(4)));
typedef unsigned long long u64;

__device__ __forceinline__ float bf2f(u16 u) {
    union { unsigned v; float f; } x; x.v = ((unsigned)u) << 16; return x.f;
}
__device__ __forceinline__ u16 f2bf(float f) {
    union { float f; unsigned v; } x; x.f = f;
    return (u16)((x.v + 0x7fffu + ((x.v >> 16) & 1u)) >> 16);
}

__device__ __forceinline__ f32x4 mfma16(u16x8 a, u16x8 b, f32x4 c) {
    return __builtin_amdgcn_mfma_f32_16x16x32_bf16(
        __builtin_bit_cast(bf16x8, a), __builtin_bit_cast(bf16x8, b), c, 0, 0, 0);
}

// AUX = cache-policy (LLVM CPol): SC0=1, SC1=16. 17 = coherent (L3) read.
template <int AUX>
__device__ __forceinline__ void gl_lds16(const void* g, void* s) {
    __builtin_amdgcn_global_load_lds(
        (const __attribute__((address_space(1))) void*)g,
        (__attribute__((address_space(3))) void*)s, 16, 0, AUX);
}

__device__ __forceinline__ float sigm(float x) { return 1.0f / (1.0f + __expf(-x)); }
__device__ __forceinline__ float tanh_fast(float x) {
    float e = __expf(2.0f * x);
    return 1.0f - 2.0f / (e + 1.0f);
}

// ---------------------------------------------------------------------------
// GEMM: C[M,N] = epi(A[M,K] * B[N,K]^T + bias), bf16 in/out, f32 accum.
// 128x128 tile, BK=64, 4 waves (2x2). LDS-bounce epilogue for coalesced C.
// ---------------------------------------------------------------------------
template <int EPI>
__global__ __launch_bounds__(256) void gemm_bt128(
    const u16* __restrict__ A, const u16* __restrict__ B,
    const float* __restrict__ bias, u16* __restrict__ C, int K, int N) {
    __shared__ __align__(16) u16 smem[128 * 136];
    u16* lA = smem;
    u16* lB = smem + 8192;
    const int lane = threadIdx.x & 63;
    const int wave = threadIdx.x >> 6;
    const int wr = wave >> 1, wc = wave & 1;
    const int bm = blockIdx.x, bn = blockIdx.y;
    f32x4 acc[4][4] = {};
    const int srow = lane >> 3;
    const int scol = (lane & 7) * 8;
    const u16* Abase = A + (size_t)(bm * 128 + srow) * K + scol;
    const u16* Bbase = B + (size_t)(bn * 128 + srow) * K + scol;

    for (int k0 = 0; k0 < K; k0 += 64) {
#pragma unroll
        for (int j = 0; j < 4; ++j) {
            int chunk = wave * 4 + j;
            gl_lds16<0>(Abase + (size_t)(chunk * 8) * K + k0, lA + chunk * 512);
            gl_lds16<0>(Bbase + (size_t)(chunk * 8) * K + k0, lB + chunk * 512);
        }
        __syncthreads();
        const u16* pA = lA + (wr * 64 + (lane & 15)) * 64 + (lane >> 4) * 8;
        const u16* pB = lB + (wc * 64 + (lane & 15)) * 64 + (lane >> 4) * 8;
#pragma unroll
        for (int kk = 0; kk < 2; ++kk) {
            u16x8 a[4], b[4];
#pragma unroll
            for (int m = 0; m < 4; ++m) a[m] = *(const u16x8*)(pA + m * 1024 + kk * 32);
#pragma unroll
            for (int n = 0; n < 4; ++n) b[n] = *(const u16x8*)(pB + n * 1024 + kk * 32);
#pragma unroll
            for (int m = 0; m < 4; ++m)
#pragma unroll
                for (int n = 0; n < 4; ++n)
                    acc[m][n] = mfma16(a[m], b[n], acc[m][n]);
        }
        __syncthreads();
    }
#pragma unroll
    for (int n = 0; n < 4; ++n) {
        int cc = wc * 64 + n * 16 + (lane & 15);
        float bv = bias[bn * 128 + cc];
#pragma unroll
        for (int m = 0; m < 4; ++m) {
            int rr = wr * 64 + m * 16 + ((lane >> 4) * 4);
#pragma unroll
            for (int i = 0; i < 4; ++i) {
                float v = acc[m][n][i] + bv;
                if (EPI == 1) v = (v >= 0.0f) ? v : 0.01f * v;
                smem[(rr + i) * 136 + cc] = f2bf(v);
            }
        }
    }
    __syncthreads();
#pragma unroll
    for (int p = 0; p < 8; ++p) {
        int rr = p * 16 + wave * 4 + (lane >> 4);
        int cc = (lane & 15) * 8;
        u16x8 v = *(const u16x8*)(smem + rr * 136 + cc);
        *(u16x8*)(C + (size_t)(bm * 128 + rr) * N + bn * 128 + cc) = v;
    }
}

// ---------------------------------------------------------------------------
// Persistent LSTM chunk kernel (R13 structure, reverted from the fusion arc).
// Grid 256 wgs x 256 thr (4 waves), 1 wg/CU.
// wg (bm=bid&3, bn=bid>>2): batch rows [bm*64,+64), gate cols [bn*64,+64).
// Wave w owns gate cols [bn*64 + w*16,+16): breg = 32 frags = 128 VGPRs.
// Chunked flag consumption (poll 16 producers per h-chunk), block h layout
// [bn][bm][row][32B] with 2KB/wg coalesced publish, R9 zero-cache-maintenance
// protocol. R16 micro-opt: value(t-1) reduce moved AFTER the flag publish --
// off the critical publish path, overlapping the next poll window. Parity
// safety: producers overwrite vpartial[(t-1)&1] no earlier than one full
// step (~9us) after flag(t); the reduce completes ~0.5us after.
// ---------------------------------------------------------------------------

// Stage one [64 rows x 512B] K-chunk kc from the BLOCK-layout h buffer.
// LDS: row-major [64][512B], content swizzled: LDS(r,cb)=G(r, kc*512+(cb^sw)).
__device__ __forceinline__ void stage_chunk_blk(const char* hinB, int bm, char* buf,
                                                int kc, int wave, int lane) {
#pragma unroll
    for (int j = 0; j < 8; ++j) {
        int hr = wave * 8 + j;                 // row-pair index 0..31
        int r = hr * 2 + (lane >> 5);          // row 0..63
        int sc = ((lane & 31) * 16) ^ ((r & 7) << 4);   // [0,512), 16B aligned
        int cbg = kc * 512 + sc;               // global byte col in h row
        gl_lds16<17>(hinB + (size_t)(cbg >> 5) * 8192 + bm * 2048 + r * 32 + (cbg & 31),
                     buf + (size_t)hr * 1024);
    }
}

__global__ __launch_bounds__(256, 1) void lstm_seq(
    const u16* __restrict__ xg, const u16* __restrict__ Whh,
    const int* __restrict__ dones, const float* __restrict__ Wv,
    u16* __restrict__ h0, u16* __restrict__ h1,
    float* __restrict__ cbuf, float* __restrict__ hbuf,
    float* __restrict__ value, int* __restrict__ flags,
    float* __restrict__ vpartial, int t0, int nt, int first) {
    __shared__ __align__(16) char sm[65536];   // 2 x 32KB chunk buffers
    float* lepi = (float*)sm;                  // [64][65] f32 = 16640B (in buf0)
    char* hbB = sm + 17408;                    // 2KB h bounce (in buf0, after lepi)
    float* vpB = (float*)(sm + 19456);         // 1KB vpartial bounce
    const int tid = threadIdx.x;
    const int lane = tid & 63, wave = tid >> 6;
    const int bm = blockIdx.x & 3, bn = blockIdx.x >> 2;   // bn 0..63
    const int sw = (lane & 7) << 4;

    // ---- Whh: wave w holds gate cols [bn*64+w*16,+16), all K -> 128 VGPRs ----
    u16x8 breg[32];
    {
        const u16* wrow = Whh + (size_t)(bn * 64 + wave * 16 + (lane & 15)) * H_DIM +
                          (lane >> 4) * 8;
#pragma unroll
        for (int s = 0; s < 32; ++s) breg[s] = *(const u16x8*)(wrow + s * 32);
    }

    // ---- per-thread epilogue state: (batch row r, 4 units) ----
    const int r = tid & 63;
    const int ublk = tid >> 6;
    const int bg = bm * 64 + r;
    const int ucol = bn * 16 + ublk * 4;
    float wv[4], c[4];
#pragma unroll
    for (int uu = 0; uu < 4; ++uu) wv[uu] = Wv[ucol + uu];
    if (first) {
        c[0] = c[1] = c[2] = c[3] = 0.0f;
    } else {
        float4 cv = *(const float4*)(cbuf + (size_t)bg * H_DIM + ucol);
        c[0] = cv.x; c[1] = cv.y; c[2] = cv.z; c[3] = cv.w;
    }

    const int rl = lane & 15;
    const int ko = (lane >> 4) * 16;

    for (int tt = 0; tt < nt; ++tt) {
        const int t = t0 + tt;
        const char* hinB = (const char*)((t & 1) ? h1 : h0);   // block layout
        u16* houtB = (t & 1) ? h0 : h1;

        // poll the 16 flags feeding h chunk kc (4 lanes per flag, all waves)
        auto poll16 = [&](int kc) {
            if (t > 0) {
                const int fi = bm * 64 + kc * 16 + (lane & 15);
                while (__hip_atomic_load(&flags[fi], __ATOMIC_RELAXED,
                                         __HIP_MEMORY_SCOPE_AGENT) < t)
                    __builtin_amdgcn_s_sleep(1);
            }
        };

        // step-constant loads (independent of flags)
        const int done = dones[t * B_DIM + bg];
        u16x4 xv[4];
#pragma unroll
        for (int uu = 0; uu < 4; ++uu)
            xv[uu] = *(const u16x4*)(xg + (size_t)tt * B_DIM * G_DIM +
                                     (size_t)bg * G_DIM + bn * 64 + (ublk * 4 + uu) * 4);

        // ---- chunk-0: poll its 16 producers, stage; poll chunk-1 under flight ----
        poll16(0);
        stage_chunk_blk(hinB, bm, sm, 0, wave, lane);
        poll16(1);
        __syncthreads();   // B1: chunk 0 fully staged (all waves)

        // ---- K-chunked, double-buffered MFMA; polls pipelined per-chunk ----
        f32x4 acc[4] = {};
#pragma unroll
        for (int kc = 0; kc < 4; ++kc) {
            char* buf = sm + (kc & 1) * 32768;
            if (kc < 3) stage_chunk_blk(hinB, bm, sm + ((kc + 1) & 1) * 32768, kc + 1,
                                        wave, lane);
#pragma unroll
            for (int s2 = 0; s2 < 8; ++s2) {
                int kb2 = s2 * 64 + ko;
#pragma unroll
                for (int m = 0; m < 4; ++m) {
                    u16x8 a = *(const u16x8*)(buf + (m * 16 + rl) * 512 + (kb2 ^ sw));
                    acc[m] = mfma16(a, breg[kc * 8 + s2], acc[m]);
                }
            }
            if (kc < 2) poll16(kc + 2);    // for next iteration's stage
            if (kc < 3) __syncthreads();   // B2..B4 (kc=3: scatter hits buf0, no barrier)
        }

        // ---- scatter gate pre-activations into lepi [64][65] (wave-local cols) ----
#pragma unroll
        for (int m = 0; m < 4; ++m)
#pragma unroll
            for (int i = 0; i < 4; ++i)
                lepi[(m * 16 + (lane >> 4) * 4 + i) * 65 + wave * 16 + rl] = acc[m][i];
        // no barrier: gate math reads only this wave's columns (lgkmcnt-ordered)

        // ---- gate math: thread = (batch row r, 4 units) ----
        const float mb = (done == 0) ? 1.0f : 0.0f;
        float vpart = 0.0f;
        u16x4 hb;
        float hf[4];
#pragma unroll
        for (int uu = 0; uu < 4; ++uu) {
            const float* gp = &lepi[r * 65 + (ublk * 4 + uu) * 4];
            float gi = bf2f(xv[uu][0]) + mb * gp[0];
            float gf = bf2f(xv[uu][1]) + mb * gp[1];
            float gg = bf2f(xv[uu][2]) + mb * gp[2];
            float go = bf2f(xv[uu][3]) + mb * gp[3];
            float i_ = sigm(gi), f_ = sigm(gf), g_ = tanh_fast(gg), o_ = sigm(go);
            float cn = f_ * (mb * c[uu]) + i_ * g_;
            float hn = o_ * tanh_fast(cn);
            c[uu] = cn; hf[uu] = hn;
            hb[uu] = f2bf(hn);
            float lr = (hn >= 0.0f) ? hn : 0.01f * hn;
            vpart += lr * wv[uu];
        }
        *(u16x4*)(hbB + r * 32 + ublk * 8) = hb;   // LDS bounce
        vpB[r * 4 + ublk] = vpart;
        if (t == T_DIM - 1)
            *(float4*)(hbuf + (size_t)bg * H_DIM + ucol) = make_float4(hf[0], hf[1], hf[2], hf[3]);
        __syncthreads();   // B5: bounce complete (cross-wave read next)

        // ---- coalesced publishes: h block 2KB (8B/thread), vpartial 1KB ----
        {
            u64 hv = *(const u64*)(hbB + tid * 8);
            __hip_atomic_store((u64*)((char*)houtB + (size_t)bn * 8192 + bm * 2048 + tid * 8),
                               hv, __ATOMIC_RELAXED, __HIP_MEMORY_SCOPE_AGENT);
            if (tid < 64) {
                const u64* pv = (const u64*)vpB + tid * 2;
                u64 v0 = pv[0], v1 = pv[1];
                float* dv = vpartial + (size_t)(t & 1) * 65536 + (size_t)bn * 1024 +
                            bm * 256 + tid * 4;
                __hip_atomic_store((u64*)dv, v0, __ATOMIC_RELAXED, __HIP_MEMORY_SCOPE_AGENT);
                __hip_atomic_store((u64*)dv + 1, v1, __ATOMIC_RELAXED, __HIP_MEMORY_SCOPE_AGENT);
            }
        }
        // ---- B6: every wave's stores drained (vmcnt(0) before barrier), then flag ----
        __syncthreads();
        if (tid == 0)
            __hip_atomic_store(&flags[bm * 64 + bn], t + 1, __ATOMIC_RELAXED,
                               __HIP_MEMORY_SCOPE_AGENT);

        // ---- value(t-1) reduce: OFF the publish path, fills the poll window.
        //      All 64 flags were confirmed >= t by this step's polls 0..3. ----
        if (t > 0 && tid < 64) {
            const float* vp = vpartial + (size_t)((t - 1) & 1) * 65536 +
                              (size_t)lane * 1024 + (size_t)(bm * 64 + bn) * 4;
            union { u64 u; float f[2]; } ua, ub;
            ua.u = __hip_atomic_load((const u64*)vp, __ATOMIC_RELAXED,
                                     __HIP_MEMORY_SCOPE_AGENT);
            ub.u = __hip_atomic_load((const u64*)(vp + 2), __ATOMIC_RELAXED,
                                     __HIP_MEMORY_SCOPE_AGENT);
            float s = ua.f[0] + ua.f[1] + ub.f[0] + ub.f[1];
#pragma unroll
            for (int m2 = 32; m2 >= 1; m2 >>= 1) s += __shfl_xor(s, m2);
            if (tid == 0) value[(t - 1) * B_DIM + bm * 64 + bn] += s;
        }
    }
    *(float4*)(cbuf + (size_t)bg * H_DIM + ucol) = make_float4(c[0], c[1], c[2], c[3]);

    // ---- final value row (t = T-1): poll all group wgs, then reduce ----
    if (t0 + nt == T_DIM && tid < 64) {
        while (__hip_atomic_load(&flags[bm * 64 + lane], __ATOMIC_RELAXED,
                                 __HIP_MEMORY_SCOPE_AGENT) < T_DIM)
            __builtin_amdgcn_s_sleep(1);
        const float* vp = vpartial + (size_t)((T_DIM - 1) & 1) * 65536 +
                          (size_t)lane * 1024 + (size_t)(bm * 64 + bn) * 4;
        union { u64 u; float f[2]; } ua, ub;
        ua.u = __hip_atomic_load((const u64*)vp, __ATOMIC_RELAXED, __HIP_MEMORY_SCOPE_AGENT);
        ub.u = __hip_atomic_load((const u64*)(vp + 2), __ATOMIC_RELAXED,
                                 __HIP_MEMORY_SCOPE_AGENT);
        float s = ua.f[0] + ua.f[1] + ub.f[0] + ub.f[1];
#pragma unroll
        for (int m2 = 32; m2 >= 1; m2 >>= 1) s += __shfl_xor(s, m2);
        if (tid == 0) value[(T_DIM - 1) * B_DIM + bm * 64 + bn] += s;
    }
}

// ---------------------------------------------------------------------------
__global__ void k_cast_bf16(const float* __restrict__ in, u16* __restrict__ out, int n4) {
    int i = blockIdx.x * 256 + threadIdx.x;
    if (i < n4) {
        float4 v = *(const float4*)(in + (size_t)i * 4);
        u16x4 o;
        o[0] = f2bf(v.x); o[1] = f2bf(v.y); o[2] = f2bf(v.z); o[3] = f2bf(v.w);
        *(u16x4*)(out + (size_t)i * 4) = o;
    }
}

__global__ void k_permute_w(const float* __restrict__ W, u16* __restrict__ Wp) {
    int row = blockIdx.x;
    int rin = (row & 3) * H_DIM + (row >> 2);
    int c = threadIdx.x * 4;
    float4 v = *(const float4*)(W + (size_t)rin * H_DIM + c);
    u16x4 o;
    o[0] = f2bf(v.x); o[1] = f2bf(v.y); o[2] = f2bf(v.z); o[3] = f2bf(v.w);
    *(u16x4*)(Wp + (size_t)row * H_DIM + c) = o;
}

__global__ void k_prep_bias(const float* __restrict__ b_ih, const float* __restrict__ b_hh,
                            float* __restrict__ bc) {
    int i = blockIdx.x * 256 + threadIdx.x;
    int n = i >> 2, q = i & 3;
    bc[i] = b_ih[q * H_DIM + n] + b_hh[q * H_DIM + n];
}

__global__ void k_init(float* __restrict__ value, const float* __restrict__ bv,
                       u16* __restrict__ h0, int* __restrict__ flags) {
    int i = blockIdx.x * 256 + threadIdx.x;
    if (i < B_DIM * H_DIM) h0[i] = 0;
    if (i < T_DIM * B_DIM) value[i] = *bv;
    if (i < 256) flags[i] = 0;
}

extern "C" void kernel_launch(void* const* d_in, const int* in_sizes, int n_in,
                              void* d_out, int out_size, void* d_ws, size_t ws_size,
                              hipStream_t stream) {
    const float* x     = (const float*)d_in[0];
    const int*   dones = (const int*)d_in[1];
    const float* W1    = (const float*)d_in[2];
    const float* b1    = (const float*)d_in[3];
    const float* W_ih  = (const float*)d_in[4];
    const float* W_hh  = (const float*)d_in[5];
    const float* b_ih  = (const float*)d_in[6];
    const float* b_hh  = (const float*)d_in[7];
    const float* Wv    = (const float*)d_in[8];
    const float* bv    = (const float*)d_in[9];

    float* out   = (float*)d_out;
    float* value = out;                          // [T*B]
    float* hbuf  = out + (size_t)T_DIM * B_DIM;  // h_T [B*H] f32
    float* cbuf  = hbuf + (size_t)B_DIM * H_DIM; // c_T [B*H] f32

    const size_t per_nt = (size_t)(F_DIM + H_DIM + G_DIM) * B_DIM * 2;
    const size_t fixed = (size_t)H_DIM * F_DIM * 2 + 2 * (size_t)G_DIM * H_DIM * 2 +
                         G_DIM * 4 + 2 * (size_t)B_DIM * H_DIM * 2 +
                         2 * 65536 * 4 + 8192;
    int nt = 2;
    for (int cand = 128; cand >= 2; cand >>= 1)
        if (fixed + (size_t)cand * per_nt + 65536 <= ws_size) { nt = cand; break; }
    if (nt > T_DIM) nt = T_DIM;

    char* ws = (char*)d_ws;
    size_t off = 0;
    auto alloc = [&](size_t bytes) {
        void* p = ws + off;
        off = (off + bytes + 255) & ~(size_t)255;
        return p;
    };
    u16*   x_bf   = (u16*)alloc((size_t)nt * B_DIM * F_DIM * 2);
    u16*   shr    = (u16*)alloc((size_t)nt * B_DIM * H_DIM * 2);
    u16*   xg     = (u16*)alloc((size_t)nt * B_DIM * G_DIM * 2);
    u16*   W1b    = (u16*)alloc((size_t)H_DIM * F_DIM * 2);
    u16*   Wihp   = (u16*)alloc((size_t)G_DIM * H_DIM * 2);
    u16*   Whhp   = (u16*)alloc((size_t)G_DIM * H_DIM * 2);
    float* bcomb  = (float*)alloc((size_t)G_DIM * 4);
    u16*   hping  = (u16*)alloc((size_t)B_DIM * H_DIM * 2);
    u16*   hpong  = (u16*)alloc((size_t)B_DIM * H_DIM * 2);
    int*   flags  = (int*)alloc(256 * 4);
    float* vpart  = (float*)alloc(2 * 65536 * 4);

    // ---- weight prep ----
    k_cast_bf16<<<(H_DIM * F_DIM / 4) / 256, 256, 0, stream>>>(W1, W1b, H_DIM * F_DIM / 4);
    k_permute_w<<<G_DIM, 256, 0, stream>>>(W_ih, Wihp);
    k_permute_w<<<G_DIM, 256, 0, stream>>>(W_hh, Whhp);
    k_prep_bias<<<G_DIM / 256, 256, 0, stream>>>(b_ih, b_hh, bcomb);
    k_init<<<(B_DIM * H_DIM) / 256, 256, 0, stream>>>(value, bv, hping, flags);

    for (int t0 = 0; t0 < T_DIM; t0 += nt) {
        int m = nt * B_DIM;
        int n4 = m * F_DIM / 4;
        k_cast_bf16<<<n4 / 256, 256, 0, stream>>>(x + (size_t)t0 * B_DIM * F_DIM, x_bf, n4);
        gemm_bt128<1><<<dim3(m / 128, H_DIM / 128), 256, 0, stream>>>(
            x_bf, W1b, b1, shr, F_DIM, H_DIM);
        gemm_bt128<0><<<dim3(m / 128, G_DIM / 128), 256, 0, stream>>>(
            shr, Wihp, bcomb, xg, H_DIM, G_DIM);

        lstm_seq<<<256, 256, 0, stream>>>(
            xg, Whhp, dones, Wv, hping, hpong, cbuf, hbuf, value, flags, vpart,
            t0, nt, (t0 == 0) ? 1 : 0);
    }
}

// Round 17
// 1492.396 us; speedup vs baseline: 1.2824x; 1.0126x over previous
//
#include <hip/hip_runtime.h>
#include <cstdint>
#include <cstddef>

#define T_DIM 128
#define B_DIM 256
#define F_DIM 512
#define H_DIM 1024
#define G_DIM 4096   // 4*H

typedef unsigned short u16;
typedef unsigned short u16x8 __attribute__((ext_vector_type(8)));
typedef unsigned short u16x4 __attribute__((ext_vector_type(4)));
typedef __bf16 bf16x8 __attribute__((ext_vector_type(8)));
typedef float f32x4 __attribute__((ext_vector_type(4)));
typedef unsigned long long u64;

__device__ __forceinline__ float bf2f(u16 u) {
    union { unsigned v; float f; } x; x.v = ((unsigned)u) << 16; return x.f;
}
__device__ __forceinline__ u16 f2bf(float f) {
    union { float f; unsigned v; } x; x.f = f;
    return (u16)((x.v + 0x7fffu + ((x.v >> 16) & 1u)) >> 16);
}

__device__ __forceinline__ f32x4 mfma16(u16x8 a, u16x8 b, f32x4 c) {
    return __builtin_amdgcn_mfma_f32_16x16x32_bf16(
        __builtin_bit_cast(bf16x8, a), __builtin_bit_cast(bf16x8, b), c, 0, 0, 0);
}

// AUX = cache-policy (LLVM CPol): SC0=1, SC1=16. 17 = coherent (L3) read.
template <int AUX>
__device__ __forceinline__ void gl_lds16(const void* g, void* s) {
    __builtin_amdgcn_global_load_lds(
        (const __attribute__((address_space(1))) void*)g,
        (__attribute__((address_space(3))) void*)s, 16, 0, AUX);
}

__device__ __forceinline__ float sigm(float x) { return 1.0f / (1.0f + __expf(-x)); }
__device__ __forceinline__ float tanh_fast(float x) {
    float e = __expf(2.0f * x);
    return 1.0f - 2.0f / (e + 1.0f);
}

// ---------------------------------------------------------------------------
// GEMM: C[M,N] = epi(A[M,K] * B[N,K]^T + bias), bf16 in/out, f32 accum.
// 128x128 tile, BK=64, 4 waves (2x2). LDS-bounce epilogue for coalesced C.
// ---------------------------------------------------------------------------
template <int EPI>
__global__ __launch_bounds__(256) void gemm_bt128(
    const u16* __restrict__ A, const u16* __restrict__ B,
    const float* __restrict__ bias, u16* __restrict__ C, int K, int N) {
    __shared__ __align__(16) u16 smem[128 * 136];
    u16* lA = smem;
    u16* lB = smem + 8192;
    const int lane = threadIdx.x & 63;
    const int wave = threadIdx.x >> 6;
    const int wr = wave >> 1, wc = wave & 1;
    const int bm = blockIdx.x, bn = blockIdx.y;
    f32x4 acc[4][4] = {};
    const int srow = lane >> 3;
    const int scol = (lane & 7) * 8;
    const u16* Abase = A + (size_t)(bm * 128 + srow) * K + scol;
    const u16* Bbase = B + (size_t)(bn * 128 + srow) * K + scol;

    for (int k0 = 0; k0 < K; k0 += 64) {
#pragma unroll
        for (int j = 0; j < 4; ++j) {
            int chunk = wave * 4 + j;
            gl_lds16<0>(Abase + (size_t)(chunk * 8) * K + k0, lA + chunk * 512);
            gl_lds16<0>(Bbase + (size_t)(chunk * 8) * K + k0, lB + chunk * 512);
        }
        __syncthreads();
        const u16* pA = lA + (wr * 64 + (lane & 15)) * 64 + (lane >> 4) * 8;
        const u16* pB = lB + (wc * 64 + (lane & 15)) * 64 + (lane >> 4) * 8;
#pragma unroll
        for (int kk = 0; kk < 2; ++kk) {
            u16x8 a[4], b[4];
#pragma unroll
            for (int m = 0; m < 4; ++m) a[m] = *(const u16x8*)(pA + m * 1024 + kk * 32);
#pragma unroll
            for (int n = 0; n < 4; ++n) b[n] = *(const u16x8*)(pB + n * 1024 + kk * 32);
#pragma unroll
            for (int m = 0; m < 4; ++m)
#pragma unroll
                for (int n = 0; n < 4; ++n)
                    acc[m][n] = mfma16(a[m], b[n], acc[m][n]);
        }
        __syncthreads();
    }
#pragma unroll
    for (int n = 0; n < 4; ++n) {
        int cc = wc * 64 + n * 16 + (lane & 15);
        float bv = bias[bn * 128 + cc];
#pragma unroll
        for (int m = 0; m < 4; ++m) {
            int rr = wr * 64 + m * 16 + ((lane >> 4) * 4);
#pragma unroll
            for (int i = 0; i < 4; ++i) {
                float v = acc[m][n][i] + bv;
                if (EPI == 1) v = (v >= 0.0f) ? v : 0.01f * v;
                smem[(rr + i) * 136 + cc] = f2bf(v);
            }
        }
    }
    __syncthreads();
#pragma unroll
    for (int p = 0; p < 8; ++p) {
        int rr = p * 16 + wave * 4 + (lane >> 4);
        int cc = (lane & 15) * 8;
        u16x8 v = *(const u16x8*)(smem + rr * 136 + cc);
        *(u16x8*)(C + (size_t)(bm * 128 + rr) * N + bn * 128 + cc) = v;
    }
}

// ---------------------------------------------------------------------------
// Persistent LSTM chunk kernel (R13 structure, reverted from the fusion arc).
// Grid 256 wgs x 256 thr (4 waves), 1 wg/CU.
// wg (bm=bid&3, bn=bid>>2): batch rows [bm*64,+64), gate cols [bn*64,+64).
// Wave w owns gate cols [bn*64 + w*16,+16): breg = 32 frags = 128 VGPRs.
// Chunked flag consumption (poll 16 producers per h-chunk), block h layout
// [bn][bm][row][32B] with 2KB/wg coalesced publish, R9 zero-cache-maintenance
// protocol. R16 micro-opt: value(t-1) reduce moved AFTER the flag publish --
// off the critical publish path, overlapping the next poll window. Parity
// safety: producers overwrite vpartial[(t-1)&1] no earlier than one full
// step (~9us) after flag(t); the reduce completes ~0.5us after.
// ---------------------------------------------------------------------------

// Stage one [64 rows x 512B] K-chunk kc from the BLOCK-layout h buffer.
// LDS: row-major [64][512B], content swizzled: LDS(r,cb)=G(r, kc*512+(cb^sw)).
__device__ __forceinline__ void stage_chunk_blk(const char* hinB, int bm, char* buf,
                                                int kc, int wave, int lane) {
#pragma unroll
    for (int j = 0; j < 8; ++j) {
        int hr = wave * 8 + j;                 // row-pair index 0..31
        int r = hr * 2 + (lane >> 5);          // row 0..63
        int sc = ((lane & 31) * 16) ^ ((r & 7) << 4);   // [0,512), 16B aligned
        int cbg = kc * 512 + sc;               // global byte col in h row
        gl_lds16<17>(hinB + (size_t)(cbg >> 5) * 8192 + bm * 2048 + r * 32 + (cbg & 31),
                     buf + (size_t)hr * 1024);
    }
}

__global__ __launch_bounds__(256, 1) void lstm_seq(
    const u16* __restrict__ xg, const u16* __restrict__ Whh,
    const int* __restrict__ dones, const float* __restrict__ Wv,
    u16* __restrict__ h0, u16* __restrict__ h1,
    float* __restrict__ cbuf, float* __restrict__ hbuf,
    float* __restrict__ value, int* __restrict__ flags,
    float* __restrict__ vpartial, int t0, int nt, int first) {
    __shared__ __align__(16) char sm[65536];   // 2 x 32KB chunk buffers
    float* lepi = (float*)sm;                  // [64][65] f32 = 16640B (in buf0)
    char* hbB = sm + 17408;                    // 2KB h bounce (in buf0, after lepi)
    float* vpB = (float*)(sm + 19456);         // 1KB vpartial bounce
    const int tid = threadIdx.x;
    const int lane = tid & 63, wave = tid >> 6;
    const int bm = blockIdx.x & 3, bn = blockIdx.x >> 2;   // bn 0..63
    const int sw = (lane & 7) << 4;

    // ---- Whh: wave w holds gate cols [bn*64+w*16,+16), all K -> 128 VGPRs ----
    u16x8 breg[32];
    {
        const u16* wrow = Whh + (size_t)(bn * 64 + wave * 16 + (lane & 15)) * H_DIM +
                          (lane >> 4) * 8;
#pragma unroll
        for (int s = 0; s < 32; ++s) breg[s] = *(const u16x8*)(wrow + s * 32);
    }

    // ---- per-thread epilogue state: (batch row r, 4 units) ----
    const int r = tid & 63;
    const int ublk = tid >> 6;
    const int bg = bm * 64 + r;
    const int ucol = bn * 16 + ublk * 4;
    float wv[4], c[4];
#pragma unroll
    for (int uu = 0; uu < 4; ++uu) wv[uu] = Wv[ucol + uu];
    if (first) {
        c[0] = c[1] = c[2] = c[3] = 0.0f;
    } else {
        float4 cv = *(const float4*)(cbuf + (size_t)bg * H_DIM + ucol);
        c[0] = cv.x; c[1] = cv.y; c[2] = cv.z; c[3] = cv.w;
    }

    const int rl = lane & 15;
    const int ko = (lane >> 4) * 16;

    for (int tt = 0; tt < nt; ++tt) {
        const int t = t0 + tt;
        const char* hinB = (const char*)((t & 1) ? h1 : h0);   // block layout
        u16* houtB = (t & 1) ? h0 : h1;

        // poll the 16 flags feeding h chunk kc (4 lanes per flag, all waves)
        auto poll16 = [&](int kc) {
            if (t > 0) {
                const int fi = bm * 64 + kc * 16 + (lane & 15);
                while (__hip_atomic_load(&flags[fi], __ATOMIC_RELAXED,
                                         __HIP_MEMORY_SCOPE_AGENT) < t)
                    __builtin_amdgcn_s_sleep(1);
            }
        };

        // step-constant loads (independent of flags)
        const int done = dones[t * B_DIM + bg];
        u16x4 xv[4];
#pragma unroll
        for (int uu = 0; uu < 4; ++uu)
            xv[uu] = *(const u16x4*)(xg + (size_t)tt * B_DIM * G_DIM +
                                     (size_t)bg * G_DIM + bn * 64 + (ublk * 4 + uu) * 4);

        // ---- chunk-0: poll its 16 producers, stage; poll chunk-1 under flight ----
        poll16(0);
        stage_chunk_blk(hinB, bm, sm, 0, wave, lane);
        poll16(1);
        __syncthreads();   // B1: chunk 0 fully staged (all waves)

        // ---- K-chunked, double-buffered MFMA; polls pipelined per-chunk ----
        f32x4 acc[4] = {};
#pragma unroll
        for (int kc = 0; kc < 4; ++kc) {
            char* buf = sm + (kc & 1) * 32768;
            if (kc < 3) stage_chunk_blk(hinB, bm, sm + ((kc + 1) & 1) * 32768, kc + 1,
                                        wave, lane);
#pragma unroll
            for (int s2 = 0; s2 < 8; ++s2) {
                int kb2 = s2 * 64 + ko;
#pragma unroll
                for (int m = 0; m < 4; ++m) {
                    u16x8 a = *(const u16x8*)(buf + (m * 16 + rl) * 512 + (kb2 ^ sw));
                    acc[m] = mfma16(a, breg[kc * 8 + s2], acc[m]);
                }
            }
            if (kc < 2) poll16(kc + 2);    // for next iteration's stage
            if (kc < 3) __syncthreads();   // B2..B4 (kc=3: scatter hits buf0, no barrier)
        }

        // ---- scatter gate pre-activations into lepi [64][65] (wave-local cols) ----
#pragma unroll
        for (int m = 0; m < 4; ++m)
#pragma unroll
            for (int i = 0; i < 4; ++i)
                lepi[(m * 16 + (lane >> 4) * 4 + i) * 65 + wave * 16 + rl] = acc[m][i];
        // no barrier: gate math reads only this wave's columns (lgkmcnt-ordered)

        // ---- gate math: thread = (batch row r, 4 units) ----
        const float mb = (done == 0) ? 1.0f : 0.0f;
        float vpart = 0.0f;
        u16x4 hb;
        float hf[4];
#pragma unroll
        for (int uu = 0; uu < 4; ++uu) {
            const float* gp = &lepi[r * 65 + (ublk * 4 + uu) * 4];
            float gi = bf2f(xv[uu][0]) + mb * gp[0];
            float gf = bf2f(xv[uu][1]) + mb * gp[1];
            float gg = bf2f(xv[uu][2]) + mb * gp[2];
            float go = bf2f(xv[uu][3]) + mb * gp[3];
            float i_ = sigm(gi), f_ = sigm(gf), g_ = tanh_fast(gg), o_ = sigm(go);
            float cn = f_ * (mb * c[uu]) + i_ * g_;
            float hn = o_ * tanh_fast(cn);
            c[uu] = cn; hf[uu] = hn;
            hb[uu] = f2bf(hn);
            float lr = (hn >= 0.0f) ? hn : 0.01f * hn;
            vpart += lr * wv[uu];
        }
        *(u16x4*)(hbB + r * 32 + ublk * 8) = hb;   // LDS bounce
        vpB[r * 4 + ublk] = vpart;
        if (t == T_DIM - 1)
            *(float4*)(hbuf + (size_t)bg * H_DIM + ucol) = make_float4(hf[0], hf[1], hf[2], hf[3]);
        __syncthreads();   // B5: bounce complete (cross-wave read next)

        // ---- coalesced publishes: h block 2KB (8B/thread), vpartial 1KB ----
        {
            u64 hv = *(const u64*)(hbB + tid * 8);
            __hip_atomic_store((u64*)((char*)houtB + (size_t)bn * 8192 + bm * 2048 + tid * 8),
                               hv, __ATOMIC_RELAXED, __HIP_MEMORY_SCOPE_AGENT);
            if (tid < 64) {
                const u64* pv = (const u64*)vpB + tid * 2;
                u64 v0 = pv[0], v1 = pv[1];
                float* dv = vpartial + (size_t)(t & 1) * 65536 + (size_t)bn * 1024 +
                            bm * 256 + tid * 4;
                __hip_atomic_store((u64*)dv, v0, __ATOMIC_RELAXED, __HIP_MEMORY_SCOPE_AGENT);
                __hip_atomic_store((u64*)dv + 1, v1, __ATOMIC_RELAXED, __HIP_MEMORY_SCOPE_AGENT);
            }
        }
        // ---- B6: every wave's stores drained (vmcnt(0) before barrier), then flag ----
        __syncthreads();
        if (tid == 0)
            __hip_atomic_store(&flags[bm * 64 + bn], t + 1, __ATOMIC_RELAXED,
                               __HIP_MEMORY_SCOPE_AGENT);

        // ---- value(t-1) reduce: OFF the publish path, fills the poll window.
        //      All 64 flags were confirmed >= t by this step's polls 0..3. ----
        if (t > 0 && tid < 64) {
            const float* vp = vpartial + (size_t)((t - 1) & 1) * 65536 +
                              (size_t)lane * 1024 + (size_t)(bm * 64 + bn) * 4;
            union { u64 u; float f[2]; } ua, ub;
            ua.u = __hip_atomic_load((const u64*)vp, __ATOMIC_RELAXED,
                                     __HIP_MEMORY_SCOPE_AGENT);
            ub.u = __hip_atomic_load((const u64*)(vp + 2), __ATOMIC_RELAXED,
                                     __HIP_MEMORY_SCOPE_AGENT);
            float s = ua.f[0] + ua.f[1] + ub.f[0] + ub.f[1];
#pragma unroll
            for (int m2 = 32; m2 >= 1; m2 >>= 1) s += __shfl_xor(s, m2);
            if (tid == 0) value[(t - 1) * B_DIM + bm * 64 + bn] += s;
        }
    }
    *(float4*)(cbuf + (size_t)bg * H_DIM + ucol) = make_float4(c[0], c[1], c[2], c[3]);

    // ---- final value row (t = T-1): poll all group wgs, then reduce ----
    if (t0 + nt == T_DIM && tid < 64) {
        while (__hip_atomic_load(&flags[bm * 64 + lane], __ATOMIC_RELAXED,
                                 __HIP_MEMORY_SCOPE_AGENT) < T_DIM)
            __builtin_amdgcn_s_sleep(1);
        const float* vp = vpartial + (size_t)((T_DIM - 1) & 1) * 65536 +
                          (size_t)lane * 1024 + (size_t)(bm * 64 + bn) * 4;
        union { u64 u; float f[2]; } ua, ub;
        ua.u = __hip_atomic_load((const u64*)vp, __ATOMIC_RELAXED, __HIP_MEMORY_SCOPE_AGENT);
        ub.u = __hip_atomic_load((const u64*)(vp + 2), __ATOMIC_RELAXED,
                                 __HIP_MEMORY_SCOPE_AGENT);
        float s = ua.f[0] + ua.f[1] + ub.f[0] + ub.f[1];
#pragma unroll
        for (int m2 = 32; m2 >= 1; m2 >>= 1) s += __shfl_xor(s, m2);
        if (tid == 0) value[(T_DIM - 1) * B_DIM + bm * 64 + bn] += s;
    }
}

// ---------------------------------------------------------------------------
__global__ void k_cast_bf16(const float* __restrict__ in, u16* __restrict__ out, int n4) {
    int i = blockIdx.x * 256 + threadIdx.x;
    if (i < n4) {
        float4 v = *(const float4*)(in + (size_t)i * 4);
        u16x4 o;
        o[0] = f2bf(v.x); o[1] = f2bf(v.y); o[2] = f2bf(v.z); o[3] = f2bf(v.w);
        *(u16x4*)(out + (size_t)i * 4) = o;
    }
}

__global__ void k_permute_w(const float* __restrict__ W, u16* __restrict__ Wp) {
    int row = blockIdx.x;
    int rin = (row & 3) * H_DIM + (row >> 2);
    int c = threadIdx.x * 4;
    float4 v = *(const float4*)(W + (size_t)rin * H_DIM + c);
    u16x4 o;
    o[0] = f2bf(v.x); o[1] = f2bf(v.y); o[2] = f2bf(v.z); o[3] = f2bf(v.w);
    *(u16x4*)(Wp + (size_t)row * H_DIM + c) = o;
}

__global__ void k_prep_bias(const float* __restrict__ b_ih, const float* __restrict__ b_hh,
                            float* __restrict__ bc) {
    int i = blockIdx.x * 256 + threadIdx.x;
    int n = i >> 2, q = i & 3;
    bc[i] = b_ih[q * H_DIM + n] + b_hh[q * H_DIM + n];
}

__global__ void k_init(float* __restrict__ value, const float* __restrict__ bv,
                       u16* __restrict__ h0, int* __restrict__ flags) {
    int i = blockIdx.x * 256 + threadIdx.x;
    if (i < B_DIM * H_DIM) h0[i] = 0;
    if (i < T_DIM * B_DIM) value[i] = *bv;
    if (i < 256) flags[i] = 0;
}

extern "C" void kernel_launch(void* const* d_in, const int* in_sizes, int n_in,
                              void* d_out, int out_size, void* d_ws, size_t ws_size,
                              hipStream_t stream) {
    const float* x     = (const float*)d_in[0];
    const int*   dones = (const int*)d_in[1];
    const float* W1    = (const float*)d_in[2];
    const float* b1    = (const float*)d_in[3];
    const float* W_ih  = (const float*)d_in[4];
    const float* W_hh  = (const float*)d_in[5];
    const float* b_ih  = (const float*)d_in[6];
    const float* b_hh  = (const float*)d_in[7];
    const float* Wv    = (const float*)d_in[8];
    const float* bv    = (const float*)d_in[9];

    float* out   = (float*)d_out;
    float* value = out;                          // [T*B]
    float* hbuf  = out + (size_t)T_DIM * B_DIM;  // h_T [B*H] f32
    float* cbuf  = hbuf + (size_t)B_DIM * H_DIM; // c_T [B*H] f32

    const size_t per_nt = (size_t)(F_DIM + H_DIM + G_DIM) * B_DIM * 2;
    const size_t fixed = (size_t)H_DIM * F_DIM * 2 + 2 * (size_t)G_DIM * H_DIM * 2 +
                         G_DIM * 4 + 2 * (size_t)B_DIM * H_DIM * 2 +
                         2 * 65536 * 4 + 8192;
    int nt = 2;
    for (int cand = 128; cand >= 2; cand >>= 1)
        if (fixed + (size_t)cand * per_nt + 65536 <= ws_size) { nt = cand; break; }
    if (nt > T_DIM) nt = T_DIM;

    char* ws = (char*)d_ws;
    size_t off = 0;
    auto alloc = [&](size_t bytes) {
        void* p = ws + off;
        off = (off + bytes + 255) & ~(size_t)255;
        return p;
    };
    u16*   x_bf   = (u16*)alloc((size_t)nt * B_DIM * F_DIM * 2);
    u16*   shr    = (u16*)alloc((size_t)nt * B_DIM * H_DIM * 2);
    u16*   xg     = (u16*)alloc((size_t)nt * B_DIM * G_DIM * 2);
    u16*   W1b    = (u16*)alloc((size_t)H_DIM * F_DIM * 2);
    u16*   Wihp   = (u16*)alloc((size_t)G_DIM * H_DIM * 2);
    u16*   Whhp   = (u16*)alloc((size_t)G_DIM * H_DIM * 2);
    float* bcomb  = (float*)alloc((size_t)G_DIM * 4);
    u16*   hping  = (u16*)alloc((size_t)B_DIM * H_DIM * 2);
    u16*   hpong  = (u16*)alloc((size_t)B_DIM * H_DIM * 2);
    int*   flags  = (int*)alloc(256 * 4);
    float* vpart  = (float*)alloc(2 * 65536 * 4);

    // ---- weight prep ----
    k_cast_bf16<<<(H_DIM * F_DIM / 4) / 256, 256, 0, stream>>>(W1, W1b, H_DIM * F_DIM / 4);
    k_permute_w<<<G_DIM, 256, 0, stream>>>(W_ih, Wihp);
    k_permute_w<<<G_DIM, 256, 0, stream>>>(W_hh, Whhp);
    k_prep_bias<<<G_DIM / 256, 256, 0, stream>>>(b_ih, b_hh, bcomb);
    k_init<<<(B_DIM * H_DIM) / 256, 256, 0, stream>>>(value, bv, hping, flags);

    for (int t0 = 0; t0 < T_DIM; t0 += nt) {
        int m = nt * B_DIM;
        int n4 = m * F_DIM / 4;
        k_cast_bf16<<<n4 / 256, 256, 0, stream>>>(x + (size_t)t0 * B_DIM * F_DIM, x_bf, n4);
        gemm_bt128<1><<<dim3(m / 128, H_DIM / 128), 256, 0, stream>>>(
            x_bf, W1b, b1, shr, F_DIM, H_DIM);
        gemm_bt128<0><<<dim3(m / 128, G_DIM / 128), 256, 0, stream>>>(
            shr, Wihp, bcomb, xg, H_DIM, G_DIM);

        lstm_seq<<<256, 256, 0, stream>>>(
            xg, Whhp, dones, Wv, hping, hpong, cbuf, hbuf, value, flags, vpart,
            t0, nt, (t0 == 0) ? 1 : 0);
    }
}